// Round 14
// baseline (676.285 us; speedup 1.0000x reference)
//
#include <hip/hip_runtime.h>
#include <hip/hip_bf16.h>

#define D_ 256
#define NH_ 8
#define HD_ 32
#define NL_ 4
#define NP_ 4
#define DFF_ 1024
#define BS_ 8
#define LQ_ 300
#define LV_ 20197
#define NQ_ (BS_*LQ_)          // 2400
#define MPAD_ 2432             // 38*64
#define NSRC_ (BS_*LV_*D_)     // 41,363,456 floats

typedef short bf16x8 __attribute__((ext_vector_type(8)));
typedef float f32x4  __attribute__((ext_vector_type(4)));

__device__ __forceinline__ float u2f(unsigned int u) {
    union { unsigned int i; float f; } v; v.i = u << 16; return v.f;
}
__device__ __forceinline__ float lo2f(unsigned int u) {
    union { unsigned int i; float f; } v; v.i = u << 16; return v.f;
}
__device__ __forceinline__ float hi2f(unsigned int u) {
    union { unsigned int i; float f; } v; v.i = u & 0xffff0000u; return v.f;
}
__device__ __forceinline__ unsigned short f2bf_bits(float f) {
    __hip_bfloat16 b = __float2bfloat16(f);
    union { __hip_bfloat16 b; unsigned short u; } v; v.b = b; return v.u;
}
__device__ __forceinline__ ushort4 cv4(float4 a) {
    ushort4 o; o.x=f2bf_bits(a.x); o.y=f2bf_bits(a.y); o.z=f2bf_bits(a.z); o.w=f2bf_bits(a.w);
    return o;
}

// ---------------- 0. ALL conversions + vpw pack in one launch ----------------
// f4 segments: src | tgt/qk 153600 | ipw 49152 | l1w 65536 | l2w 65536
//            | opw 16384 | outw 16384 | sow 16384 | aww 8192 | biases 96
#define S0_ 10340864
#define S1_ 10494464
#define S2_ 10543616
#define S3_ 10609152
#define S4_ 10674688
#define S5_ 10691072
#define S6_ 10707456
#define S7_ 10723840
#define S8_ 10732032
#define S9_ 10732128
__global__ __launch_bounds__(256) void cvt_all_kernel(
    const float4* __restrict__ src, const float4* __restrict__ tgt,
    const float4* __restrict__ qp,  const float4* __restrict__ ipw,
    const float4* __restrict__ l1w, const float4* __restrict__ l2w,
    const float4* __restrict__ opw, const float4* __restrict__ outw,
    const float4* __restrict__ sow, const float4* __restrict__ aww,
    const float4* __restrict__ sob, const float4* __restrict__ awb,
    const float4* __restrict__ vpw,
    ushort4* __restrict__ vbf,    ushort4* __restrict__ tgt_bf,
    ushort4* __restrict__ qk_bf,  ushort4* __restrict__ ipw_bf,
    ushort4* __restrict__ l1w_bf, ushort4* __restrict__ l2w_bf,
    ushort4* __restrict__ opw_bf, ushort4* __restrict__ outw_bf,
    ushort4* __restrict__ sow_bf, ushort4* __restrict__ aww_bf,
    float4* __restrict__ sawb,    float4* __restrict__ vpwP)
{
    __shared__ float4 tile[32][33];
    if (blockIdx.x < 16) {   // vpw float4-transpose (8x2 tiles of 32x32)
        const int by = blockIdx.x >> 1, bx = blockIdx.x & 1;
        const int tx = threadIdx.x & 31, ty = threadIdx.x >> 5;
#pragma unroll
        for (int i = 0; i < 32; i += 8)
            tile[ty+i][tx] = vpw[(size_t)(by*32+ty+i)*64 + bx*32+tx];
        __syncthreads();
#pragma unroll
        for (int i = 0; i < 32; i += 8)
            vpwP[(size_t)(bx*32+ty+i)*256 + by*32+tx] = tile[tx][ty+i];
    }
    for (int i = blockIdx.x*256 + threadIdx.x; i < S9_; i += 2048*256) {
        if (i < S0_) { vbf[i] = cv4(src[i]); }
        else if (i < S1_) {
            int j = i - S0_;
            float4 a = tgt[j], b = qp[j];
            tgt_bf[j] = cv4(a);
            qk_bf[j]  = cv4(make_float4(a.x+b.x, a.y+b.y, a.z+b.z, a.w+b.w));
        }
        else if (i < S2_) { int j = i - S1_; ipw_bf[j]  = cv4(ipw[j]); }
        else if (i < S3_) { int j = i - S2_; l1w_bf[j]  = cv4(l1w[j]); }
        else if (i < S4_) { int j = i - S3_; l2w_bf[j]  = cv4(l2w[j]); }
        else if (i < S5_) { int j = i - S4_; opw_bf[j]  = cv4(opw[j]); }
        else if (i < S6_) { int j = i - S5_; outw_bf[j] = cv4(outw[j]); }
        else if (i < S7_) { int j = i - S6_; sow_bf[j]  = cv4(sow[j]); }
        else if (i < S8_) { int j = i - S7_; aww_bf[j]  = cv4(aww[j]); }
        else { int j = i - S8_; sawb[j] = (j < 64) ? sob[j] : awb[j-64]; }
    }
}

// ---------------- G. generic bf16 MFMA GEMM with A-select by n_base ----------
// out[M,Nld] = A[M,K] @ W[N,K]^T + b. 64x64 tile, 4 waves x (16 x 64).
__global__ __launch_bounds__(256) void gemm_bf16_kernel(
    const unsigned short* __restrict__ A,   // used when n_base < nsplit
    const unsigned short* __restrict__ A2,  // used when n_base >= nsplit
    const unsigned short* __restrict__ W,   // [N, K] bf16
    const float* __restrict__ bias,         // [N]
    float* __restrict__ out,                // [NQ_, Nld] fp32 or null
    unsigned short* __restrict__ out_bf,    // [MPAD_, Nld] bf16 or null
    const int K, const int Nld, const int relu, const int nsplit)
{
    const int t = threadIdx.x, wv = t >> 6, l = t & 63;
    const int m_base = blockIdx.x*64 + wv*16;
    const int n_base = blockIdx.y*64;
    const int lr = l & 15, lg = l >> 4;
    const unsigned short* Au = (n_base < nsplit) ? A : A2;
    const unsigned short* ap = Au + (size_t)(m_base + lr)*K + lg*8;
    const unsigned short* wp = W + (size_t)(n_base + lr)*K + lg*8;
    f32x4 ac0 = {0,0,0,0}, ac1 = {0,0,0,0}, ac2 = {0,0,0,0}, ac3 = {0,0,0,0};
    for (int k = 0; k < K; k += 32) {
        bf16x8 a  = *(const bf16x8*)(ap + k);
        bf16x8 b0 = *(const bf16x8*)(wp + k);
        bf16x8 b1 = *(const bf16x8*)(wp + (size_t)16*K + k);
        bf16x8 b2 = *(const bf16x8*)(wp + (size_t)32*K + k);
        bf16x8 b3 = *(const bf16x8*)(wp + (size_t)48*K + k);
        ac0 = __builtin_amdgcn_mfma_f32_16x16x32_bf16(a, b0, ac0, 0, 0, 0);
        ac1 = __builtin_amdgcn_mfma_f32_16x16x32_bf16(a, b1, ac1, 0, 0, 0);
        ac2 = __builtin_amdgcn_mfma_f32_16x16x32_bf16(a, b2, ac2, 0, 0, 0);
        ac3 = __builtin_amdgcn_mfma_f32_16x16x32_bf16(a, b3, ac3, 0, 0, 0);
    }
    const int orow0 = m_base + lg*4;
    const int ocol  = n_base + lr;
    const float b0v = bias[ocol], b1v = bias[ocol+16],
                b2v = bias[ocol+32], b3v = bias[ocol+48];
#pragma unroll
    for (int j = 0; j < 4; ++j) {
        const int row = orow0 + j;
        if (row < NQ_) {
            float v0 = ac0[j] + b0v, v1 = ac1[j] + b1v,
                  v2 = ac2[j] + b2v, v3 = ac3[j] + b3v;
            if (relu) {
                v0 = fmaxf(v0, 0.f); v1 = fmaxf(v1, 0.f);
                v2 = fmaxf(v2, 0.f); v3 = fmaxf(v3, 0.f);
            }
            const size_t base = (size_t)row*Nld + ocol;
            if (out) {
                out[base]    = v0; out[base+16] = v1;
                out[base+32] = v2; out[base+48] = v3;
            }
            if (out_bf) {
                out_bf[base]    = f2bf_bits(v0); out_bf[base+16] = f2bf_bits(v1);
                out_bf[base+32] = f2bf_bits(v2); out_bf[base+48] = f2bf_bits(v3);
            }
        }
    }
}

// ---------------- GL. fused GEMM (N=256) + bias + residual + LayerNorm ----------
// One block = 64 rows x all 256 cols (16 acc/wave). Row-LN via 16-lane shfl.
__global__ __launch_bounds__(256) void gemm_ln_kernel(
    const unsigned short* __restrict__ A,   // [MPAD_, K] bf16
    const unsigned short* __restrict__ W,   // [256, K] bf16
    const float* __restrict__ bias, const float* __restrict__ res,
    const float* __restrict__ gw, const float* __restrict__ gb,
    float* __restrict__ out,                // fp32 [NQ_,256]
    const float* __restrict__ qp,           // optional
    unsigned short* __restrict__ outq_bf,   // optional bf16(out+qp)
    unsigned short* __restrict__ out_bf,    // optional bf16(out)
    const int K)
{
    const int t = threadIdx.x, wv = t >> 6, l = t & 63;
    const int m_base = blockIdx.x*64 + wv*16;
    const int lr = l & 15, lg = l >> 4;
    const unsigned short* ap = A + (size_t)(m_base + lr)*K + lg*8;
    const unsigned short* wp = W + (size_t)lr*K + lg*8;
    f32x4 acc[16];
#pragma unroll
    for (int nt = 0; nt < 16; ++nt) acc[nt] = (f32x4){0,0,0,0};
    for (int k = 0; k < K; k += 32) {
        bf16x8 a = *(const bf16x8*)(ap + k);
#pragma unroll
        for (int nt = 0; nt < 16; ++nt) {
            bf16x8 b = *(const bf16x8*)(wp + (size_t)nt*16*K + k);
            acc[nt] = __builtin_amdgcn_mfma_f32_16x16x32_bf16(a, b, acc[nt], 0, 0, 0);
        }
    }
    float bl[16], gwl[16], gbl[16];
#pragma unroll
    for (int nt = 0; nt < 16; ++nt) {
        const int col = nt*16 + lr;
        bl[nt] = bias[col]; gwl[nt] = gw[col]; gbl[nt] = gb[col];
    }
#pragma unroll
    for (int j = 0; j < 4; ++j) {
        const int row = m_base + lg*4 + j;
        const bool valid = row < NQ_;
        float v[16];
        float s = 0.f, ss = 0.f;
#pragma unroll
        for (int nt = 0; nt < 16; ++nt) {
            float r = valid ? res[(size_t)row*256 + nt*16 + lr] : 0.f;
            v[nt] = acc[nt][j] + bl[nt] + r;
            s += v[nt]; ss += v[nt]*v[nt];
        }
#pragma unroll
        for (int off = 1; off < 16; off <<= 1) {
            s += __shfl_xor(s, off); ss += __shfl_xor(ss, off);
        }
        const float mean = s * (1.0f/256.0f);
        const float var  = ss * (1.0f/256.0f) - mean*mean;
        const float rs   = rsqrtf(var + 1e-5f);
        if (valid) {
#pragma unroll
            for (int nt = 0; nt < 16; ++nt) {
                const int col = nt*16 + lr;
                const size_t idx = (size_t)row*256 + col;
                const float o = (v[nt]-mean)*rs*gwl[nt] + gbl[nt];
                out[idx] = o;
                if (outq_bf) outq_bf[idx] = f2bf_bits(o + qp[idx]);
                if (out_bf)  out_bf[idx]  = f2bf_bits(o);
            }
        }
    }
}

// ---------------- 2. Self attention (fused qkv buffer [m][768]) ----------------
__global__ __launch_bounds__(256) void attn_kernel(
    const float* __restrict__ qkv, unsigned short* __restrict__ sa_bf)
{
    __shared__ unsigned short khl[LQ_][HD_+2];
    __shared__ unsigned short vhl[LQ_][HD_+2];
    __shared__ float sc[4][LQ_];
    __shared__ float qbuf[4][HD_];
    const int b = blockIdx.x >> 3, h = blockIdx.x & 7, chunk = blockIdx.y;
    const int t = threadIdx.x, w = t >> 6, lane = t & 63;
    for (int i = t; i < LQ_*HD_; i += 256) {
        int kq = i >> 5, d = i & 31;
        khl[kq][d] = f2bf_bits(qkv[(size_t)(b*LQ_ + kq)*768 + 256 + h*HD_ + d]);
        vhl[kq][d] = f2bf_bits(qkv[(size_t)(b*LQ_ + kq)*768 + 512 + h*HD_ + d]);
    }
    __syncthreads();
    const float scale = 0.17677669529663687f;  // 1/sqrt(32)
    for (int qi = 0; qi < 15; ++qi) {
        const int q = chunk*60 + w*15 + qi;
        if (lane < HD_) qbuf[w][lane] = qkv[(size_t)(b*LQ_ + q)*768 + h*HD_ + lane];
        float qv[HD_];
#pragma unroll
        for (int d2 = 0; d2 < HD_; ++d2) qv[d2] = qbuf[w][d2];
        float mx = -1e30f;
        for (int k = lane; k < LQ_; k += 64) {
            float s = 0.f;
#pragma unroll
            for (int d2 = 0; d2 < HD_; ++d2) s += qv[d2]*u2f(khl[k][d2]);
            s *= scale;
            sc[w][k] = s;
            mx = fmaxf(mx, s);
        }
#pragma unroll
        for (int off = 32; off; off >>= 1) mx = fmaxf(mx, __shfl_xor(mx, off));
        float lsum = 0.f;
        for (int k = lane; k < LQ_; k += 64) {
            float e = __expf(sc[w][k] - mx);
            sc[w][k] = e; lsum += e;
        }
#pragma unroll
        for (int off = 32; off; off >>= 1) lsum += __shfl_xor(lsum, off);
        const int d = lane & 31, half = lane >> 5;
        float acc = 0.f;
        for (int k = half*150; k < half*150 + 150; ++k) acc += sc[w][k]*u2f(vhl[k][d]);
        acc += __shfl_down(acc, 32);
        if (lane < 32) sa_bf[(size_t)(b*LQ_ + q)*D_ + h*HD_ + d] = f2bf_bits(acc / lsum);
    }
}

// ---------------- 5. sampling: epilogue(loc/aw) + gather, fused ----------------
// Phase 1 computes loc (refp + so/nrm) and aw (16-group softmax) inline from
// so_awl[m][384], writes locout/awout outputs, then gathers (R5-proven schedule).
__global__ __launch_bounds__(256) void samp_fuse_bf16_kernel(
    const unsigned short* __restrict__ vbf,
    const float* __restrict__ so_awl, const float* __restrict__ refp,
    float* __restrict__ locout, float* __restrict__ awout,
    float* __restrict__ svec_g, float* __restrict__ wsum_g)
{
    __shared__ int   cidx[128][4];
    __shared__ float cwt[128][4];
    const int m = blockIdx.x, t = threadIdx.x;
    const int b = m / LQ_;

    if (t < 128) {   // t = pt = h*16 + l*4 + p
        const int l = (t >> 2) & 3;
        const int HS[4] = {100,50,25,13}, WS[4] = {152,76,38,19}, S0[4] = {0,15200,19000,19950};
        const int Hh = HS[l], Ww = WS[l], s0 = S0[l];
        // aw: softmax over the 16-point group (lanes aligned to groups of 16)
        const float logit = so_awl[(size_t)m*384 + 256 + t];
        float mx = logit;
#pragma unroll
        for (int off = 1; off < 16; off <<= 1) mx = fmaxf(mx, __shfl_xor(mx, off));
        float e = __expf(logit - mx), esum = e;
#pragma unroll
        for (int off = 1; off < 16; off <<= 1) esum += __shfl_xor(esum, off);
        const float aw = e / esum;
        awout[(size_t)m*128 + t] = aw;
        // loc
        const float locx = refp[(m*NL_ + l)*2 + 0] + so_awl[(size_t)m*384 + 2*t]     / (float)Ww;
        const float locy = refp[(m*NL_ + l)*2 + 1] + so_awl[(size_t)m*384 + 2*t + 1] / (float)Hh;
        locout[(size_t)m*256 + 2*t]     = locx;
        locout[(size_t)m*256 + 2*t + 1] = locy;
        const float x = locx*Ww - 0.5f;
        const float y = locy*Hh - 0.5f;
        const float x0f = floorf(x), y0f = floorf(y);
        const int x0 = (int)x0f, y0 = (int)y0f;
        const float fx = x - x0f, fy = y - y0f;
        const int   cx[4] = {x0, x0+1, x0,   x0+1};
        const int   cy[4] = {y0, y0,   y0+1, y0+1};
        const float cw[4] = {(1.f-fx)*(1.f-fy), fx*(1.f-fy), (1.f-fx)*fy, fx*fy};
        float sw = 0.f;
#pragma unroll
        for (int j = 0; j < 4; ++j) {
            const bool valid = (cx[j] >= 0) & (cx[j] < Ww) & (cy[j] >= 0) & (cy[j] < Hh);
            cidx[t][j] = valid ? (s0 + cy[j]*Ww + cx[j]) : s0;
            float wv = valid ? aw*cw[j] : 0.f;
            cwt[t][j] = wv;
            sw += wv;
        }
#pragma unroll
        for (int off = 8; off; off >>= 1) sw += __shfl_xor(sw, off);
        if ((t & 15) == 0) wsum_g[m*NH_ + (t >> 4)] = sw;
    }
    __syncthreads();

    const int hh = (t >> 7) * 4;
    const int c  = t & 127;
    const unsigned int* sb = (const unsigned int*)(vbf + (size_t)b*LV_*D_) + c;
#pragma unroll
    for (int h = hh; h < hh + 4; ++h) {
        float e0=0.f, e1=0.f, e2=0.f, e3=0.f;
        float o0=0.f, o1=0.f, o2=0.f, o3=0.f;
#pragma unroll 4
        for (int s = 0; s < 16; ++s) {
            const int base = h*16 + s;
            const int   i0 = cidx[base][0], i1 = cidx[base][1],
                        i2 = cidx[base][2], i3 = cidx[base][3];
            const float w0 = cwt[base][0], w1 = cwt[base][1],
                        w2 = cwt[base][2], w3 = cwt[base][3];
            const unsigned int u0 = sb[(size_t)i0*128];
            const unsigned int u1 = sb[(size_t)i1*128];
            const unsigned int u2 = sb[(size_t)i2*128];
            const unsigned int u3 = sb[(size_t)i3*128];
            e0 += w0*lo2f(u0); o0 += w0*hi2f(u0);
            e1 += w1*lo2f(u1); o1 += w1*hi2f(u1);
            e2 += w2*lo2f(u2); o2 += w2*hi2f(u2);
            e3 += w3*lo2f(u3); o3 += w3*hi2f(u3);
        }
        *(float2*)&svec_g[(size_t)m*(NH_*D_) + h*D_ + 2*c] =
            make_float2((e0+e1)+(e2+e3), (o0+o1)+(o2+o3));
    }
}

// ---------------- 5c. per-head value projection (packed fp32 weights) -> bf16 ----
__global__ __launch_bounds__(256) void vproj_kernel(
    const float* __restrict__ svec_g, const float* __restrict__ wsum_g,
    const float4* __restrict__ vpwP, const float* __restrict__ vpb,
    unsigned short* __restrict__ vo_bf)
{
    __shared__ float sv[4][NH_*D_];    // 32 KB
    const int t = threadIdx.x, m0 = blockIdx.x * 4;
    for (int i = t; i < 4*NH_*D_; i += 256)
        sv[i >> 11][i & 2047] = svec_g[(size_t)m0*(NH_*D_) + i];
    __syncthreads();
    const int h = t >> 5;
    const float4* w4 = vpwP + t;
    float a0 = 0.f, a1 = 0.f, a2 = 0.f, a3 = 0.f;
    for (int c = 0; c < 64; ++c) {
        const float4 wq = w4[c*256];
        const float4 s0 = *(const float4*)&sv[0][h*D_ + c*4];
        const float4 s1 = *(const float4*)&sv[1][h*D_ + c*4];
        const float4 s2 = *(const float4*)&sv[2][h*D_ + c*4];
        const float4 s3 = *(const float4*)&sv[3][h*D_ + c*4];
        a0 += wq.x*s0.x + wq.y*s0.y + wq.z*s0.z + wq.w*s0.w;
        a1 += wq.x*s1.x + wq.y*s1.y + wq.z*s1.z + wq.w*s1.w;
        a2 += wq.x*s2.x + wq.y*s2.y + wq.z*s2.z + wq.w*s2.w;
        a3 += wq.x*s3.x + wq.y*s3.y + wq.z*s3.z + wq.w*s3.w;
    }
    const float bb = vpb[t];
    vo_bf[(size_t)(m0+0)*D_ + t] = f2bf_bits(a0 + bb*wsum_g[(m0+0)*NH_ + h]);
    vo_bf[(size_t)(m0+1)*D_ + t] = f2bf_bits(a1 + bb*wsum_g[(m0+1)*NH_ + h]);
    vo_bf[(size_t)(m0+2)*D_ + t] = f2bf_bits(a2 + bb*wsum_g[(m0+2)*NH_ + h]);
    vo_bf[(size_t)(m0+3)*D_ + t] = f2bf_bits(a3 + bb*wsum_g[(m0+3)*NH_ + h]);
}

extern "C" void kernel_launch(void* const* d_in, const int* in_sizes, int n_in,
                              void* d_out, int out_size, void* d_ws, size_t ws_size,
                              hipStream_t stream) {
    (void)in_sizes; (void)n_in; (void)out_size; (void)ws_size;
    const float* tgt  = (const float*)d_in[0];
    const float* qpos = (const float*)d_in[1];
    const float* refp = (const float*)d_in[2];
    const float* srcp = (const float*)d_in[3];
    const float* ipw  = (const float*)d_in[4];
    const float* ipb  = (const float*)d_in[5];
    const float* opw  = (const float*)d_in[6];
    const float* opb  = (const float*)d_in[7];
    const float* sow  = (const float*)d_in[8];
    const float* sob  = (const float*)d_in[9];
    const float* aww  = (const float*)d_in[10];
    const float* awb  = (const float*)d_in[11];
    const float* vpw  = (const float*)d_in[12];
    const float* vpb  = (const float*)d_in[13];
    const float* outw = (const float*)d_in[14];
    const float* outb = (const float*)d_in[15];
    const float* l1w  = (const float*)d_in[16];
    const float* l1b  = (const float*)d_in[17];
    const float* l2w  = (const float*)d_in[18];
    const float* l2b  = (const float*)d_in[19];
    const float* n1w  = (const float*)d_in[20];
    const float* n1b  = (const float*)d_in[21];
    const float* n2w  = (const float*)d_in[22];
    const float* n2b  = (const float*)d_in[23];
    const float* n3w  = (const float*)d_in[24];
    const float* n3b  = (const float*)d_in[25];

    // ---- workspace layout (floats), audited disjoint ----
    float* wsf = (float*)d_ws;
    float* qkv_buf = wsf;                              //        0 .. 1,843,200
    float* x1      = wsf + 1843200;                    // 1,843,200 .. 2,457,600
    float* x2      = wsf + 2457600;                    // 2,457,600 .. 3,072,000
    float* so_awl  = wsf + 3072000;                    // 3,072,000 .. 3,993,600
    unsigned short* hid_bf  = (unsigned short*)(wsf + 3993600);   // 1,245,184 f
    unsigned short* tgt_bf  = (unsigned short*)(wsf + 5238784);   // 311,296 f
    unsigned short* qk_bf   = (unsigned short*)(wsf + 5550080);   // 311,296 f
    unsigned short* sa_bf   = (unsigned short*)(wsf + 5861376);   // 311,296 f
    unsigned short* x1q_bf  = (unsigned short*)(wsf + 6172672);   // 311,296 f
    unsigned short* vo_bf   = (unsigned short*)(wsf + 6483968);   // 311,296 f
    unsigned short* x2_bf   = (unsigned short*)(wsf + 6795264);   // 311,296 f
    unsigned short* ipw_bf  = (unsigned short*)(wsf + 7106560);   //  98,304 f
    unsigned short* l1w_bf  = (unsigned short*)(wsf + 7204864);   // 131,072 f
    unsigned short* l2w_bf  = (unsigned short*)(wsf + 7335936);   // 131,072 f
    unsigned short* opw_bf  = (unsigned short*)(wsf + 7467008);   //  32,768 f
    unsigned short* outw_bf = (unsigned short*)(wsf + 7499776);   //  32,768 f
    unsigned short* sow_bf  = (unsigned short*)(wsf + 7532544);   //  32,768 f
    unsigned short* aww_bf  = (unsigned short*)(wsf + 7565312);   //  16,384 f (contiguous after sow_bf)
    float* sawb = wsf + 7581696;                                  //     384 f
    float4* vpwP = (float4*)(wsf + 7582080);                      //  65,536 f
    unsigned short* vbf = (unsigned short*)(wsf + 7647616);       // 20,681,728 f
    float* svec_g = wsf + 7647616 + 20681728;                     // = 28,329,344 (4,915,200 f)
    float* wsum_g = svec_g + 4915200;                             // 33,244,544 .. 33,263,744

    float* xout   = (float*)d_out;            // x   (8,300,256)
    float* locout = xout + 614400;            // loc (8,300,8,4,4,2)
    float* awout  = xout + 1228800;           // aw  (8,300,8,4,4)

    cvt_all_kernel<<<2048, 256, 0, stream>>>(
        (const float4*)srcp, (const float4*)tgt, (const float4*)qpos,
        (const float4*)ipw, (const float4*)l1w, (const float4*)l2w,
        (const float4*)opw, (const float4*)outw, (const float4*)sow,
        (const float4*)aww, (const float4*)sob, (const float4*)awb,
        (const float4*)vpw,
        (ushort4*)vbf, (ushort4*)tgt_bf, (ushort4*)qk_bf, (ushort4*)ipw_bf,
        (ushort4*)l1w_bf, (ushort4*)l2w_bf, (ushort4*)opw_bf, (ushort4*)outw_bf,
        (ushort4*)sow_bf, (ushort4*)aww_bf, (float4*)sawb, vpwP);

    // QKV: single GEMM, N=768; A = qk_bf for n<512 (q,k), tgt_bf for n>=512 (v)
    gemm_bf16_kernel<<<dim3(38, 12), 256, 0, stream>>>(
        qk_bf, tgt_bf, ipw_bf, ipb, qkv_buf, nullptr, 256, 768, 0, 512);

    attn_kernel<<<dim3(BS_*NH_, 5), 256, 0, stream>>>(qkv_buf, sa_bf);

    // out-proj + residual(tgt) + LN(norm2) -> x1, x1q_bf
    gemm_ln_kernel<<<38, 256, 0, stream>>>(sa_bf, opw_bf, opb, tgt, n2w, n2b,
                                           x1, qpos, x1q_bf, nullptr, 256);

    // sampling params: one N=384 GEMM (sow|aww concat)
    gemm_bf16_kernel<<<dim3(38, 6), 256, 0, stream>>>(
        x1q_bf, x1q_bf, sow_bf, sawb, so_awl, nullptr, 256, 384, 0, 1<<30);

    samp_fuse_bf16_kernel<<<NQ_, 256, 0, stream>>>(vbf, so_awl, refp,
                                                   locout, awout, svec_g, wsum_g);
    vproj_kernel<<<NQ_/4, 256, 0, stream>>>(svec_g, wsum_g, vpwP, vpb, vo_bf);

    // output-proj + residual(x1) + LN(norm1) -> x2, x2_bf
    gemm_ln_kernel<<<38, 256, 0, stream>>>(vo_bf, outw_bf, outb, x1, n1w, n1b,
                                           x2, nullptr, nullptr, x2_bf, 256);

    // FFN1 (relu) via MFMA
    gemm_bf16_kernel<<<dim3(38, 16), 256, 0, stream>>>(
        x2_bf, x2_bf, l1w_bf, l1b, nullptr, hid_bf, 256, 1024, 1, 1<<30);
    // FFN2 + residual(x2) + LN(norm3) -> xout
    gemm_ln_kernel<<<38, 256, 0, stream>>>(hid_bf, l2w_bf, l2b, x2, n3w, n3b,
                                           xout, nullptr, nullptr, nullptr, 1024);
}